// Round 7
// baseline (435.285 us; speedup 1.0000x reference)
//
#include <hip/hip_runtime.h>
#include <hip/hip_bf16.h>
#include <math.h>
#include <stdint.h>

// InfoNCE fused: sim = A @ B^T / T  (8192x8192x512, fp32 in)
// loss = mean_i( logsumexp_j sim[i,j] - sim[i,i] )
// R7: MX-fp8 (e4m3, unit scales) mfma_scale 16x16x128, BK=128 chunks,
// XOR-swizzled LDS (conflict-free), stateless per-tile LSE, fp32 diag.

#define NB 8192
#define DDIM 512
#define SPLITS 16
#define BM 128
#define BN 128
#define BKC 128                  // k per staged chunk (one MFMA K)
#define CPB (NB / SPLITS)        // 512 cols per block
#define TPB (CPB / BN)           // 4 col tiles per block
#define NPART (SPLITS * TPB * 2) // 128 (m,l) partials per row

typedef unsigned char u8;
typedef __attribute__((ext_vector_type(4))) int i32x4;
typedef __attribute__((ext_vector_type(8))) int i32x8;
typedef __attribute__((ext_vector_type(4))) float f32x4;

// global -> LDS direct copy, 16B per lane: HW writes ldsbase + lane*16.
__device__ __forceinline__ void gl2lds16(const u8* g, const u8* l) {
  __builtin_amdgcn_global_load_lds(
      (__attribute__((address_space(1))) unsigned int*)(uintptr_t)g,
      (__attribute__((address_space(3))) unsigned int*)(unsigned int)(uintptr_t)l,
      16, 0, 0);
}

// One wave per row: convert a & p rows to fp8 e4m3 (OCP), diag dot in fp32.
__global__ void cvt_diag_kernel(const float* __restrict__ a, const float* __restrict__ p,
                                u8* __restrict__ af8, u8* __restrict__ pf8,
                                float* __restrict__ diag, float* __restrict__ out) {
  if (blockIdx.x == 0 && threadIdx.x == 0) out[0] = 0.f;
  int row = (blockIdx.x * 256 + threadIdx.x) >> 6;
  int lane = threadIdx.x & 63;
  const float4* ar = (const float4*)(a + (size_t)row * DDIM + lane * 8);
  const float4* pr = (const float4*)(p + (size_t)row * DDIM + lane * 8);
  float4 a0 = ar[0], a1 = ar[1];
  float4 p0 = pr[0], p1 = pr[1];
  int va0 = __builtin_amdgcn_cvt_pk_fp8_f32(a0.x, a0.y, 0, false);
  va0 = __builtin_amdgcn_cvt_pk_fp8_f32(a0.z, a0.w, va0, true);
  int va1 = __builtin_amdgcn_cvt_pk_fp8_f32(a1.x, a1.y, 0, false);
  va1 = __builtin_amdgcn_cvt_pk_fp8_f32(a1.z, a1.w, va1, true);
  int vp0 = __builtin_amdgcn_cvt_pk_fp8_f32(p0.x, p0.y, 0, false);
  vp0 = __builtin_amdgcn_cvt_pk_fp8_f32(p0.z, p0.w, vp0, true);
  int vp1 = __builtin_amdgcn_cvt_pk_fp8_f32(p1.x, p1.y, 0, false);
  vp1 = __builtin_amdgcn_cvt_pk_fp8_f32(p1.z, p1.w, vp1, true);
  *(int2*)(af8 + (size_t)row * DDIM + lane * 8) = (int2){va0, va1};
  *(int2*)(pf8 + (size_t)row * DDIM + lane * 8) = (int2){vp0, vp1};
  float s = a0.x * p0.x + a0.y * p0.y + a0.z * p0.z + a0.w * p0.w +
            a1.x * p1.x + a1.y * p1.y + a1.z * p1.z + a1.w * p1.w;
  for (int off = 32; off > 0; off >>= 1) s += __shfl_down(s, off);
  if (lane == 0) diag[row] = s * 10.0f;  // / T
}

__global__ __launch_bounds__(256, 4) void gemm_lse(
    const u8* __restrict__ Af8, const u8* __restrict__ Bf8,
    float* __restrict__ partM, float* __restrict__ partL) {
  // LDS: one 128-row x 128-k fp8 chunk per operand (16 KB each).
  // XOR swizzle: 16B octet o of row r stored at octet o ^ (r&7).
  __shared__ u8 sA[BM * BKC];   // 16 KB
  __shared__ u8 sB[BN * BKC];   // 16 KB

  const int tid = threadIdx.x;
  const int wave = tid >> 6;
  const int lane = tid & 63;
  const int quad = lane >> 4;
  const int l16 = lane & 15;
  const int wr = wave >> 1, wc = wave & 1;  // 2x2 wave grid, each 64x64

  // XCD-aware remap: xcd = bid&7 gets row-tiles {xcd, xcd+8, ...}.
  const int bid = blockIdx.y * 64 + blockIdx.x;
  const int xcd = bid & 7;
  const int idx = bid >> 3;                 // 0..127
  const int rowTile = (idx & 7) * 8 + xcd;  // 0..63
  const int colSplit = idx >> 3;            // 0..15
  const int row0 = rowTile * BM;
  const int col0 = colSplit * CPB;

  // Staging: load c = wave*4+j covers rows c*8..c*8+7 (1 KB each).
  // Lane: row c*8 + (lane>>3), stored octet p = lane&7, source octet
  // q = p ^ (row&7). Source bytes = row*512 + kk*128 + q*16.
  const int rsub = lane >> 3;
  const int qsrc = (lane & 7) ^ rsub;
  const u8* aBase[4];
  const u8* ldsA[4];
  const u8* ldsB[4];
#pragma unroll
  for (int j = 0; j < 4; ++j) {
    int c = wave * 4 + j;
    aBase[j] = Af8 + (size_t)(row0 + c * 8 + rsub) * DDIM + qsrc * 16;
    ldsA[j] = &sA[c * 1024];
    ldsB[j] = &sB[c * 1024];
  }

  // Fragment reads: row R = w*64 + mi*16 + l16 (R&7 == l16&7), k-octet
  // o = quad*2 + h stored at o ^ (l16&7); 16B each -> two ds_read_b128.
  const int s7 = l16 & 7;
  const int oLo = ((quad * 2) ^ s7) * 16;
  const int oHi = ((quad * 2 + 1) ^ s7) * 16;
  const u8* pa0 = &sA[(wr * 64 + l16) * BKC];
  const u8* pb0 = &sB[(wc * 64 + l16) * BKC];

  for (int t = 0; t < TPB; ++t) {
    const u8* bBase[4];
#pragma unroll
    for (int j = 0; j < 4; ++j)
      bBase[j] = Bf8 + (size_t)(col0 + t * BN + (wave * 4 + j) * 8 + rsub) * DDIM + qsrc * 16;

    f32x4 acc[4][4];
#pragma unroll
    for (int mi = 0; mi < 4; ++mi)
#pragma unroll
      for (int ni = 0; ni < 4; ++ni) acc[mi][ni] = (f32x4){0.f, 0.f, 0.f, 0.f};

    for (int kk = 0; kk < DDIM; kk += BKC) {
      __syncthreads();  // previous chunk's readers done
#pragma unroll
      for (int j = 0; j < 4; ++j) {
        gl2lds16(aBase[j] + kk, ldsA[j]);
        gl2lds16(bBase[j] + kk, ldsB[j]);
      }
      __syncthreads();  // staging complete (barrier drains vmcnt)

      i32x8 af[4], bq[4];
#pragma unroll
      for (int i = 0; i < 4; ++i) {
        i32x4 lo = *(const i32x4*)(pa0 + i * 16 * BKC + oLo);
        i32x4 hi = *(const i32x4*)(pa0 + i * 16 * BKC + oHi);
        af[i] = (i32x8){lo[0], lo[1], lo[2], lo[3], hi[0], hi[1], hi[2], hi[3]};
        i32x4 blo = *(const i32x4*)(pb0 + i * 16 * BKC + oLo);
        i32x4 bhi = *(const i32x4*)(pb0 + i * 16 * BKC + oHi);
        bq[i] = (i32x8){blo[0], blo[1], blo[2], blo[3], bhi[0], bhi[1], bhi[2], bhi[3]};
      }
#pragma unroll
      for (int mi = 0; mi < 4; ++mi)
#pragma unroll
        for (int ni = 0; ni < 4; ++ni)
          acc[mi][ni] = __builtin_amdgcn_mfma_scale_f32_16x16x128_f8f6f4(
              af[mi], bq[ni], acc[mi][ni], 0, 0,        // cbsz=fp8, blgp=fp8
              0, 0x7F7F7F7F, 0, 0x7F7F7F7F);            // unit E8M0 scales
    }

    // Stateless per-tile LSE: shfl-merge over 16 l16 lanes (64 cols), lane
    // l16==0 writes this tile's (m,l) partial. Layout [p][row] (coalesced).
    const int p = (colSplit * TPB + t) * 2 + wc;
#pragma unroll
    for (int mi = 0; mi < 4; ++mi) {
#pragma unroll
      for (int r = 0; r < 4; ++r) {
        float v0 = acc[mi][0][r] * 10.0f;  // apply 1/T
        float v1 = acc[mi][1][r] * 10.0f;
        float v2 = acc[mi][2][r] * 10.0f;
        float v3 = acc[mi][3][r] * 10.0f;
        float mx = fmaxf(fmaxf(v0, v1), fmaxf(v2, v3));
        mx = fmaxf(mx, __shfl_xor(mx, 1));
        mx = fmaxf(mx, __shfl_xor(mx, 2));
        mx = fmaxf(mx, __shfl_xor(mx, 4));
        mx = fmaxf(mx, __shfl_xor(mx, 8));
        float s = __expf(v0 - mx) + __expf(v1 - mx) + __expf(v2 - mx) + __expf(v3 - mx);
        s += __shfl_xor(s, 1);
        s += __shfl_xor(s, 2);
        s += __shfl_xor(s, 4);
        s += __shfl_xor(s, 8);
        if (l16 == 0) {
          int row = row0 + wr * 64 + mi * 16 + quad * 4 + r;
          partM[(size_t)p * NB + row] = mx;
          partL[(size_t)p * NB + row] = s;
        }
      }
    }
  }
}

// One row per thread, 32 blocks; block-sum -> atomicAdd.
__global__ void reduce_kernel(const float* __restrict__ partM,
                              const float* __restrict__ partL,
                              const float* __restrict__ diag, float* __restrict__ out) {
  __shared__ float red[4];
  int r = blockIdx.x * 256 + threadIdx.x;
  float M = -INFINITY;
  for (int s = 0; s < NPART; ++s) M = fmaxf(M, partM[(size_t)s * NB + r]);
  float L = 0.f;
  for (int s = 0; s < NPART; ++s)
    L += partL[(size_t)s * NB + r] * __expf(partM[(size_t)s * NB + r] - M);
  float v = M + __logf(L) - diag[r];
  for (int off = 32; off > 0; off >>= 1) v += __shfl_down(v, off);
  if ((threadIdx.x & 63) == 0) red[threadIdx.x >> 6] = v;
  __syncthreads();
  if (threadIdx.x == 0) {
    float s = (red[0] + red[1] + red[2] + red[3]) * (1.0f / (float)NB);
    atomicAdd(out, s);
  }
}

extern "C" void kernel_launch(void* const* d_in, const int* in_sizes, int n_in,
                              void* d_out, int out_size, void* d_ws, size_t ws_size,
                              hipStream_t stream) {
  const float* anchor = (const float*)d_in[0];
  const float* positive = (const float*)d_in[1];
  float* out = (float*)d_out;

  char* ws = (char*)d_ws;
  u8* Af8 = (u8*)ws;                                     // 4 MB
  u8* Bf8 = (u8*)(ws + (size_t)4194304);                 // 4 MB
  float* diag = (float*)(ws + (size_t)8388608);          // 32 KB
  float* partM = (float*)(ws + (size_t)8388608 + 32768);             // 4 MB
  float* partL = (float*)(ws + (size_t)8388608 + 32768 + (size_t)NPART * NB * 4);

  cvt_diag_kernel<<<NB / 4, 256, 0, stream>>>(anchor, positive, Af8, Bf8, diag, out);
  gemm_lse<<<dim3(64, SPLITS), 256, 0, stream>>>(Af8, Bf8, partM, partL);
  reduce_kernel<<<NB / 256, 256, 0, stream>>>(partM, partL, diag, out);
}

// Round 8
// 368.699 us; speedup vs baseline: 1.1806x; 1.1806x over previous
//
#include <hip/hip_runtime.h>
#include <hip/hip_bf16.h>
#include <math.h>
#include <stdint.h>

// InfoNCE fused: sim = A @ B^T / T  (8192x8192x512, fp32 in)
// loss = mean_i( logsumexp_j sim[i,j] - sim[i,i] )
// R8: R7 (MX-fp8 e4m3, unit scales, 16x16x128) with the spill fixed:
// launch_bounds(256,3), streamed A-fragments, no pointer arrays.

#define NB 8192
#define DDIM 512
#define SPLITS 16
#define BM 128
#define BN 128
#define BKC 128                  // k per staged chunk (one MFMA K)
#define CPB (NB / SPLITS)        // 512 cols per block
#define TPB (CPB / BN)           // 4 col tiles per block
#define NPART (SPLITS * TPB * 2) // 128 (m,l) partials per row

typedef unsigned char u8;
typedef __attribute__((ext_vector_type(4))) int i32x4;
typedef __attribute__((ext_vector_type(8))) int i32x8;
typedef __attribute__((ext_vector_type(4))) float f32x4;

// global -> LDS direct copy, 16B per lane: HW writes ldsbase + lane*16.
__device__ __forceinline__ void gl2lds16(const u8* g, const u8* l) {
  __builtin_amdgcn_global_load_lds(
      (__attribute__((address_space(1))) unsigned int*)(uintptr_t)g,
      (__attribute__((address_space(3))) unsigned int*)(unsigned int)(uintptr_t)l,
      16, 0, 0);
}

// One wave per row: convert a & p rows to fp8 e4m3 (OCP), diag dot in fp32.
__global__ void cvt_diag_kernel(const float* __restrict__ a, const float* __restrict__ p,
                                u8* __restrict__ af8, u8* __restrict__ pf8,
                                float* __restrict__ diag, float* __restrict__ out) {
  if (blockIdx.x == 0 && threadIdx.x == 0) out[0] = 0.f;
  int row = (blockIdx.x * 256 + threadIdx.x) >> 6;
  int lane = threadIdx.x & 63;
  const float4* ar = (const float4*)(a + (size_t)row * DDIM + lane * 8);
  const float4* pr = (const float4*)(p + (size_t)row * DDIM + lane * 8);
  float4 a0 = ar[0], a1 = ar[1];
  float4 p0 = pr[0], p1 = pr[1];
  int va0 = __builtin_amdgcn_cvt_pk_fp8_f32(a0.x, a0.y, 0, false);
  va0 = __builtin_amdgcn_cvt_pk_fp8_f32(a0.z, a0.w, va0, true);
  int va1 = __builtin_amdgcn_cvt_pk_fp8_f32(a1.x, a1.y, 0, false);
  va1 = __builtin_amdgcn_cvt_pk_fp8_f32(a1.z, a1.w, va1, true);
  int vp0 = __builtin_amdgcn_cvt_pk_fp8_f32(p0.x, p0.y, 0, false);
  vp0 = __builtin_amdgcn_cvt_pk_fp8_f32(p0.z, p0.w, vp0, true);
  int vp1 = __builtin_amdgcn_cvt_pk_fp8_f32(p1.x, p1.y, 0, false);
  vp1 = __builtin_amdgcn_cvt_pk_fp8_f32(p1.z, p1.w, vp1, true);
  *(int2*)(af8 + (size_t)row * DDIM + lane * 8) = (int2){va0, va1};
  *(int2*)(pf8 + (size_t)row * DDIM + lane * 8) = (int2){vp0, vp1};
  float s = a0.x * p0.x + a0.y * p0.y + a0.z * p0.z + a0.w * p0.w +
            a1.x * p1.x + a1.y * p1.y + a1.z * p1.z + a1.w * p1.w;
  for (int off = 32; off > 0; off >>= 1) s += __shfl_down(s, off);
  if (lane == 0) diag[row] = s * 10.0f;  // / T
}

__global__ __launch_bounds__(256, 3) void gemm_lse(
    const u8* __restrict__ Af8, const u8* __restrict__ Bf8,
    float* __restrict__ partM, float* __restrict__ partL) {
  // LDS: one 128-row x 128-k fp8 chunk per operand (16 KB each).
  // XOR swizzle: 16B octet o of row r stored at octet o ^ (r&7).
  __shared__ u8 sA[BM * BKC];   // 16 KB
  __shared__ u8 sB[BN * BKC];   // 16 KB

  const int tid = threadIdx.x;
  const int wave = tid >> 6;
  const int lane = tid & 63;
  const int quad = lane >> 4;
  const int l16 = lane & 15;
  const int wr = wave >> 1, wc = wave & 1;  // 2x2 wave grid, each 64x64

  // XCD-aware remap: xcd = bid&7 gets row-tiles {xcd, xcd+8, ...}.
  const int bid = blockIdx.y * 64 + blockIdx.x;
  const int xcd = bid & 7;
  const int idx = bid >> 3;                 // 0..127
  const int rowTile = (idx & 7) * 8 + xcd;  // 0..63
  const int colSplit = idx >> 3;            // 0..15
  const int row0 = rowTile * BM;
  const int col0 = colSplit * CPB;

  // Staging: load j covers rows wave*32 + j*8 + rsub (1 KB LDS per load).
  // Lane: stored octet p = lane&7, source octet q = p ^ (row&7).
  const int rsub = lane >> 3;
  const int qsrc = (lane & 7) ^ rsub;
  const u8* aBase = Af8 + (size_t)(row0 + wave * 32 + rsub) * DDIM + qsrc * 16;
  const u8* ldsA = &sA[wave * 4096];
  const u8* ldsB = &sB[wave * 4096];

  // Fragment reads: row R = w*64 + i*16 + l16 (R&7 == l16&7), k-octet
  // o = quad*2 + h stored at o ^ (l16&7); 16B each -> two ds_read_b128.
  const int s7 = l16 & 7;
  const int oLo = ((quad * 2) ^ s7) * 16;
  const int oHi = ((quad * 2 + 1) ^ s7) * 16;
  const u8* pa0 = &sA[(wr * 64 + l16) * BKC];
  const u8* pb0 = &sB[(wc * 64 + l16) * BKC];

  for (int t = 0; t < TPB; ++t) {
    const u8* bBase = Bf8 + (size_t)(col0 + t * BN + wave * 32 + rsub) * DDIM + qsrc * 16;

    f32x4 acc[4][4];
#pragma unroll
    for (int mi = 0; mi < 4; ++mi)
#pragma unroll
      for (int ni = 0; ni < 4; ++ni) acc[mi][ni] = (f32x4){0.f, 0.f, 0.f, 0.f};

    for (int kk = 0; kk < DDIM; kk += BKC) {
      __syncthreads();  // previous chunk's readers done
#pragma unroll
      for (int j = 0; j < 4; ++j) {
        gl2lds16(aBase + j * 4096 + kk, ldsA + j * 1024);
        gl2lds16(bBase + j * 4096 + kk, ldsB + j * 1024);
      }
      __syncthreads();  // staging complete (barrier drains vmcnt)

      i32x8 bq[4];
#pragma unroll
      for (int ni = 0; ni < 4; ++ni) {
        i32x4 lo = *(const i32x4*)(pb0 + ni * 16 * BKC + oLo);
        i32x4 hi = *(const i32x4*)(pb0 + ni * 16 * BKC + oHi);
        bq[ni] = (i32x8){lo[0], lo[1], lo[2], lo[3], hi[0], hi[1], hi[2], hi[3]};
      }
#pragma unroll
      for (int mi = 0; mi < 4; ++mi) {
        i32x4 lo = *(const i32x4*)(pa0 + mi * 16 * BKC + oLo);
        i32x4 hi = *(const i32x4*)(pa0 + mi * 16 * BKC + oHi);
        i32x8 af = (i32x8){lo[0], lo[1], lo[2], lo[3], hi[0], hi[1], hi[2], hi[3]};
#pragma unroll
        for (int ni = 0; ni < 4; ++ni)
          acc[mi][ni] = __builtin_amdgcn_mfma_scale_f32_16x16x128_f8f6f4(
              af, bq[ni], acc[mi][ni], 0, 0,            // cbsz=fp8, blgp=fp8
              0, 0x7F7F7F7F, 0, 0x7F7F7F7F);            // unit E8M0 scales
      }
    }

    // Stateless per-tile LSE: shfl-merge over 16 l16 lanes (64 cols), lane
    // l16==0 writes this tile's (m,l) partial. Layout [p][row] (coalesced).
    const int p = (colSplit * TPB + t) * 2 + wc;
#pragma unroll
    for (int mi = 0; mi < 4; ++mi) {
#pragma unroll
      for (int r = 0; r < 4; ++r) {
        float v0 = acc[mi][0][r] * 10.0f;  // apply 1/T
        float v1 = acc[mi][1][r] * 10.0f;
        float v2 = acc[mi][2][r] * 10.0f;
        float v3 = acc[mi][3][r] * 10.0f;
        float mx = fmaxf(fmaxf(v0, v1), fmaxf(v2, v3));
        mx = fmaxf(mx, __shfl_xor(mx, 1));
        mx = fmaxf(mx, __shfl_xor(mx, 2));
        mx = fmaxf(mx, __shfl_xor(mx, 4));
        mx = fmaxf(mx, __shfl_xor(mx, 8));
        float s = __expf(v0 - mx) + __expf(v1 - mx) + __expf(v2 - mx) + __expf(v3 - mx);
        s += __shfl_xor(s, 1);
        s += __shfl_xor(s, 2);
        s += __shfl_xor(s, 4);
        s += __shfl_xor(s, 8);
        if (l16 == 0) {
          int row = row0 + wr * 64 + mi * 16 + quad * 4 + r;
          partM[(size_t)p * NB + row] = mx;
          partL[(size_t)p * NB + row] = s;
        }
      }
    }
  }
}

// One row per thread, 32 blocks; block-sum -> atomicAdd.
__global__ void reduce_kernel(const float* __restrict__ partM,
                              const float* __restrict__ partL,
                              const float* __restrict__ diag, float* __restrict__ out) {
  __shared__ float red[4];
  int r = blockIdx.x * 256 + threadIdx.x;
  float M = -INFINITY;
  for (int s = 0; s < NPART; ++s) M = fmaxf(M, partM[(size_t)s * NB + r]);
  float L = 0.f;
  for (int s = 0; s < NPART; ++s)
    L += partL[(size_t)s * NB + r] * __expf(partM[(size_t)s * NB + r] - M);
  float v = M + __logf(L) - diag[r];
  for (int off = 32; off > 0; off >>= 1) v += __shfl_down(v, off);
  if ((threadIdx.x & 63) == 0) red[threadIdx.x >> 6] = v;
  __syncthreads();
  if (threadIdx.x == 0) {
    float s = (red[0] + red[1] + red[2] + red[3]) * (1.0f / (float)NB);
    atomicAdd(out, s);
  }
}

extern "C" void kernel_launch(void* const* d_in, const int* in_sizes, int n_in,
                              void* d_out, int out_size, void* d_ws, size_t ws_size,
                              hipStream_t stream) {
  const float* anchor = (const float*)d_in[0];
  const float* positive = (const float*)d_in[1];
  float* out = (float*)d_out;

  char* ws = (char*)d_ws;
  u8* Af8 = (u8*)ws;                                     // 4 MB
  u8* Bf8 = (u8*)(ws + (size_t)4194304);                 // 4 MB
  float* diag = (float*)(ws + (size_t)8388608);          // 32 KB
  float* partM = (float*)(ws + (size_t)8388608 + 32768);             // 4 MB
  float* partL = (float*)(ws + (size_t)8388608 + 32768 + (size_t)NPART * NB * 4);

  cvt_diag_kernel<<<NB / 4, 256, 0, stream>>>(anchor, positive, Af8, Bf8, diag, out);
  gemm_lse<<<dim3(64, SPLITS), 256, 0, stream>>>(Af8, Bf8, partM, partL);
  reduce_kernel<<<NB / 256, 256, 0, stream>>>(partM, partL, diag, out);
}

// Round 9
// 186.707 us; speedup vs baseline: 2.3314x; 1.9747x over previous
//
#include <hip/hip_runtime.h>
#include <hip/hip_bf16.h>
#include <math.h>
#include <stdint.h>

// InfoNCE fused: sim = A @ B^T / T  (8192x8192x512, fp32 in)
// loss = mean_i( logsumexp_j sim[i,j] - sim[i,i] )
// R9: int8 MFMA (mfma_i32_16x16x64_i8, 2x bf16 rate, i32x4 frags = R6's
// register profile). Per-tensor quant Delta=0.045, exact i32 accum.

#define NB 8192
#define DDIM 512
#define SPLITS 16
#define BM 128
#define BN 128
#define BKC 64                   // k per staged chunk (one MFMA K)
#define CPB (NB / SPLITS)        // 512 cols per block
#define TPB (CPB / BN)           // 4 col tiles per block
#define NPART (SPLITS * TPB * 2) // 128 (m,l) partials per row

#define DELTA 0.045f
#define INV_DELTA (1.0f / DELTA)
#define OUT_SCALE (DELTA * DELTA * 10.0f)   // dequant * 1/T

typedef unsigned char u8;
typedef __attribute__((ext_vector_type(4))) int i32x4;
typedef __attribute__((ext_vector_type(4))) float f32x4;

// global -> LDS direct copy, 16B per lane: HW writes ldsbase + lane*16.
__device__ __forceinline__ void gl2lds16(const u8* g, const u8* l) {
  __builtin_amdgcn_global_load_lds(
      (__attribute__((address_space(1))) unsigned int*)(uintptr_t)g,
      (__attribute__((address_space(3))) unsigned int*)(unsigned int)(uintptr_t)l,
      16, 0, 0);
}

__device__ __forceinline__ unsigned pack4(float x0, float x1, float x2, float x3) {
  int q0 = min(127, max(-127, __float2int_rn(x0 * INV_DELTA)));
  int q1 = min(127, max(-127, __float2int_rn(x1 * INV_DELTA)));
  int q2 = min(127, max(-127, __float2int_rn(x2 * INV_DELTA)));
  int q3 = min(127, max(-127, __float2int_rn(x3 * INV_DELTA)));
  return (q0 & 0xFF) | ((q1 & 0xFF) << 8) | ((q2 & 0xFF) << 16) | ((q3 & 0xFF) << 24);
}

// One wave per row: quantize a & p rows to int8, diag dot in fp32; zero out.
__global__ void cvt_diag_kernel(const float* __restrict__ a, const float* __restrict__ p,
                                u8* __restrict__ aq, u8* __restrict__ pq,
                                float* __restrict__ diag, float* __restrict__ out) {
  if (blockIdx.x == 0 && threadIdx.x == 0) out[0] = 0.f;
  int row = (blockIdx.x * 256 + threadIdx.x) >> 6;
  int lane = threadIdx.x & 63;
  const float4* ar = (const float4*)(a + (size_t)row * DDIM + lane * 8);
  const float4* pr = (const float4*)(p + (size_t)row * DDIM + lane * 8);
  float4 a0 = ar[0], a1 = ar[1];
  float4 p0 = pr[0], p1 = pr[1];
  *(uint2*)(aq + (size_t)row * DDIM + lane * 8) =
      (uint2){pack4(a0.x, a0.y, a0.z, a0.w), pack4(a1.x, a1.y, a1.z, a1.w)};
  *(uint2*)(pq + (size_t)row * DDIM + lane * 8) =
      (uint2){pack4(p0.x, p0.y, p0.z, p0.w), pack4(p1.x, p1.y, p1.z, p1.w)};
  float s = a0.x * p0.x + a0.y * p0.y + a0.z * p0.z + a0.w * p0.w +
            a1.x * p1.x + a1.y * p1.y + a1.z * p1.z + a1.w * p1.w;
  for (int off = 32; off > 0; off >>= 1) s += __shfl_down(s, off);
  if (lane == 0) diag[row] = s * 10.0f;  // / T (exact fp32, not quantized)
}

__global__ __launch_bounds__(256, 4) void gemm_lse(
    const u8* __restrict__ Aq, const u8* __restrict__ Bq,
    float* __restrict__ partM, float* __restrict__ partL) {
  // LDS: 128 rows x 64 i8-k per operand (8 KB each). Rows are 64B (4 octets).
  // Swizzle: 16B octet o of row R stored at o ^ ((R>>1)&3) -> fragment reads
  // land 2 lanes per 4-bank group (free); staging coalesced.
  __shared__ u8 sA[BM * BKC];   // 8 KB
  __shared__ u8 sB[BN * BKC];   // 8 KB

  const int tid = threadIdx.x;
  const int wave = tid >> 6;
  const int lane = tid & 63;
  const int quad = lane >> 4;
  const int l16 = lane & 15;
  const int wr = wave >> 1, wc = wave & 1;  // 2x2 wave grid, each 64x64

  // XCD-aware remap: xcd = bid&7 gets row-tiles {xcd, xcd+8, ...}.
  const int bid = blockIdx.y * 64 + blockIdx.x;
  const int xcd = bid & 7;
  const int idx = bid >> 3;                 // 0..127
  const int rowTile = (idx & 7) * 8 + xcd;  // 0..63
  const int colSplit = idx >> 3;            // 0..15
  const int row0 = rowTile * BM;
  const int col0 = colSplit * CPB;

  // Staging: load (wave, j) fills 1KB = rows (wave*2+j)*16 + (lane>>2),
  // stored octet p = lane&3, source octet q = p ^ ((rsub>>1)&3).
  const int rsub = lane >> 2;
  const int qsrc = (lane & 3) ^ ((rsub >> 1) & 3);
  const u8* aBase = Aq + (size_t)(row0 + wave * 32 + rsub) * DDIM + qsrc * 16;
  const u8* ldsA = &sA[wave * 2048];
  const u8* ldsB = &sB[wave * 2048];

  // Fragment reads: row R = w*64 + i*16 + l16; k-octet quad stored at
  // quad ^ ((l16>>1)&3); one ds_read_b128 per fragment.
  const int sw = (l16 >> 1) & 3;
  const u8* pa0 = &sA[(wr * 64 + l16) * BKC + ((quad ^ sw) * 16)];
  const u8* pb0 = &sB[(wc * 64 + l16) * BKC + ((quad ^ sw) * 16)];

  for (int t = 0; t < TPB; ++t) {
    const u8* bBase = Bq + (size_t)(col0 + t * BN + wave * 32 + rsub) * DDIM + qsrc * 16;

    i32x4 acc[4][4];
#pragma unroll
    for (int mi = 0; mi < 4; ++mi)
#pragma unroll
      for (int ni = 0; ni < 4; ++ni) acc[mi][ni] = (i32x4){0, 0, 0, 0};

    for (int kk = 0; kk < DDIM; kk += BKC) {
      __syncthreads();  // previous chunk's readers done
#pragma unroll
      for (int j = 0; j < 2; ++j) {
        gl2lds16(aBase + j * 16 * DDIM + kk, ldsA + j * 1024);
        gl2lds16(bBase + j * 16 * DDIM + kk, ldsB + j * 1024);
      }
      __syncthreads();  // staging complete (barrier drains vmcnt)

      i32x4 af[4], bq[4];
#pragma unroll
      for (int i = 0; i < 4; ++i) {
        af[i] = *(const i32x4*)(pa0 + i * 16 * BKC);
        bq[i] = *(const i32x4*)(pb0 + i * 16 * BKC);
      }
#pragma unroll
      for (int mi = 0; mi < 4; ++mi)
#pragma unroll
        for (int ni = 0; ni < 4; ++ni)
          acc[mi][ni] =
              __builtin_amdgcn_mfma_i32_16x16x64_i8(af[mi], bq[ni], acc[mi][ni], 0, 0, 0);
    }

    // Stateless per-tile LSE: dequant+1/T, shfl-merge over 16 l16 lanes,
    // lane l16==0 writes (m,l) partial. Layout [p][row] (coalesced).
    const int p = (colSplit * TPB + t) * 2 + wc;
#pragma unroll
    for (int mi = 0; mi < 4; ++mi) {
#pragma unroll
      for (int r = 0; r < 4; ++r) {
        float v0 = (float)acc[mi][0][r] * OUT_SCALE;
        float v1 = (float)acc[mi][1][r] * OUT_SCALE;
        float v2 = (float)acc[mi][2][r] * OUT_SCALE;
        float v3 = (float)acc[mi][3][r] * OUT_SCALE;
        float mx = fmaxf(fmaxf(v0, v1), fmaxf(v2, v3));
        mx = fmaxf(mx, __shfl_xor(mx, 1));
        mx = fmaxf(mx, __shfl_xor(mx, 2));
        mx = fmaxf(mx, __shfl_xor(mx, 4));
        mx = fmaxf(mx, __shfl_xor(mx, 8));
        float s = __expf(v0 - mx) + __expf(v1 - mx) + __expf(v2 - mx) + __expf(v3 - mx);
        s += __shfl_xor(s, 1);
        s += __shfl_xor(s, 2);
        s += __shfl_xor(s, 4);
        s += __shfl_xor(s, 8);
        if (l16 == 0) {
          int row = row0 + wr * 64 + mi * 16 + quad * 4 + r;
          partM[(size_t)p * NB + row] = mx;
          partL[(size_t)p * NB + row] = s;
        }
      }
    }
  }
}

// One row per thread, 32 blocks; block-sum -> atomicAdd.
__global__ void reduce_kernel(const float* __restrict__ partM,
                              const float* __restrict__ partL,
                              const float* __restrict__ diag, float* __restrict__ out) {
  __shared__ float red[4];
  int r = blockIdx.x * 256 + threadIdx.x;
  float M = -INFINITY;
  for (int s = 0; s < NPART; ++s) M = fmaxf(M, partM[(size_t)s * NB + r]);
  float L = 0.f;
  for (int s = 0; s < NPART; ++s)
    L += partL[(size_t)s * NB + r] * __expf(partM[(size_t)s * NB + r] - M);
  float v = M + __logf(L) - diag[r];
  for (int off = 32; off > 0; off >>= 1) v += __shfl_down(v, off);
  if ((threadIdx.x & 63) == 0) red[threadIdx.x >> 6] = v;
  __syncthreads();
  if (threadIdx.x == 0) {
    float s = (red[0] + red[1] + red[2] + red[3]) * (1.0f / (float)NB);
    atomicAdd(out, s);
  }
}

extern "C" void kernel_launch(void* const* d_in, const int* in_sizes, int n_in,
                              void* d_out, int out_size, void* d_ws, size_t ws_size,
                              hipStream_t stream) {
  const float* anchor = (const float*)d_in[0];
  const float* positive = (const float*)d_in[1];
  float* out = (float*)d_out;

  char* ws = (char*)d_ws;
  u8* Aq = (u8*)ws;                                      // 4 MB
  u8* Bq = (u8*)(ws + (size_t)4194304);                  // 4 MB
  float* diag = (float*)(ws + (size_t)8388608);          // 32 KB
  float* partM = (float*)(ws + (size_t)8388608 + 32768);             // 4 MB
  float* partL = (float*)(ws + (size_t)8388608 + 32768 + (size_t)NPART * NB * 4);

  cvt_diag_kernel<<<NB / 4, 256, 0, stream>>>(anchor, positive, Aq, Bq, diag, out);
  gemm_lse<<<dim3(64, SPLITS), 256, 0, stream>>>(Aq, Bq, partM, partL);
  reduce_kernel<<<NB / 256, 256, 0, stream>>>(partM, partL, diag, out);
}

// Round 10
// 157.747 us; speedup vs baseline: 2.7594x; 1.1836x over previous
//
#include <hip/hip_runtime.h>
#include <hip/hip_bf16.h>
#include <math.h>
#include <stdint.h>

// InfoNCE fused: sim = A @ B^T / T  (8192x8192x512, fp32 in)
// loss = mean_i( logsumexp_j sim[i,j] - sim[i,i] )
// R10: int8 MFMA (R9) + BKC=128 double-chunk staging (half the barriers,
// two 64B-row half-buffers keeping R9's measured-zero-conflict swizzle)
// + per-block LSE merge in LDS (NPART 128 -> 16, light reduce).

#define NB 8192
#define DDIM 512
#define SPLITS 16
#define BM 128
#define BN 128
#define BKC 128                  // k per staged round (2 MFMA k-steps)
#define CPB (NB / SPLITS)        // 512 cols per block
#define TPB (CPB / BN)           // 4 col tiles per block
#define NPART SPLITS             // one (m,l) per row per block

#define DELTA 0.045f
#define INV_DELTA (1.0f / DELTA)
#define OUT_SCALE (DELTA * DELTA * 10.0f)   // dequant * 1/T

typedef unsigned char u8;
typedef __attribute__((ext_vector_type(4))) int i32x4;

// global -> LDS direct copy, 16B per lane: HW writes ldsbase + lane*16.
__device__ __forceinline__ void gl2lds16(const u8* g, const u8* l) {
  __builtin_amdgcn_global_load_lds(
      (__attribute__((address_space(1))) unsigned int*)(uintptr_t)g,
      (__attribute__((address_space(3))) unsigned int*)(unsigned int)(uintptr_t)l,
      16, 0, 0);
}

__device__ __forceinline__ unsigned pack4(float x0, float x1, float x2, float x3) {
  int q0 = min(127, max(-127, __float2int_rn(x0 * INV_DELTA)));
  int q1 = min(127, max(-127, __float2int_rn(x1 * INV_DELTA)));
  int q2 = min(127, max(-127, __float2int_rn(x2 * INV_DELTA)));
  int q3 = min(127, max(-127, __float2int_rn(x3 * INV_DELTA)));
  return (q0 & 0xFF) | ((q1 & 0xFF) << 8) | ((q2 & 0xFF) << 16) | ((q3 & 0xFF) << 24);
}

// One wave per row: quantize a & p rows to int8, diag dot in fp32; zero out.
__global__ void cvt_diag_kernel(const float* __restrict__ a, const float* __restrict__ p,
                                u8* __restrict__ aq, u8* __restrict__ pq,
                                float* __restrict__ diag, float* __restrict__ out) {
  if (blockIdx.x == 0 && threadIdx.x == 0) out[0] = 0.f;
  int row = (blockIdx.x * 256 + threadIdx.x) >> 6;
  int lane = threadIdx.x & 63;
  const float4* ar = (const float4*)(a + (size_t)row * DDIM + lane * 8);
  const float4* pr = (const float4*)(p + (size_t)row * DDIM + lane * 8);
  float4 a0 = ar[0], a1 = ar[1];
  float4 p0 = pr[0], p1 = pr[1];
  *(uint2*)(aq + (size_t)row * DDIM + lane * 8) =
      (uint2){pack4(a0.x, a0.y, a0.z, a0.w), pack4(a1.x, a1.y, a1.z, a1.w)};
  *(uint2*)(pq + (size_t)row * DDIM + lane * 8) =
      (uint2){pack4(p0.x, p0.y, p0.z, p0.w), pack4(p1.x, p1.y, p1.z, p1.w)};
  float s = a0.x * p0.x + a0.y * p0.y + a0.z * p0.z + a0.w * p0.w +
            a1.x * p1.x + a1.y * p1.y + a1.z * p1.z + a1.w * p1.w;
  for (int off = 32; off > 0; off >>= 1) s += __shfl_down(s, off);
  if (lane == 0) diag[row] = s * 10.0f;  // / T (exact fp32, not quantized)
}

__global__ __launch_bounds__(256, 4) void gemm_lse(
    const u8* __restrict__ Aq, const u8* __restrict__ Bq,
    float* __restrict__ partM, float* __restrict__ partL) {
  // Two 64B-row half-buffers per operand, R9's proven swizzle in each:
  // 16B octet o of row R stored at o ^ ((R>>1)&3); zero measured conflicts.
  __shared__ u8 sA[2][BM * 64];   // 16 KB
  __shared__ u8 sB[2][BN * 64];   // 16 KB
  __shared__ float sPm[2 * TPB][BM];  // 4 KB: per-tile (m) partials
  __shared__ float sPs[2 * TPB][BM];  // 4 KB

  const int tid = threadIdx.x;
  const int wave = tid >> 6;
  const int lane = tid & 63;
  const int quad = lane >> 4;
  const int l16 = lane & 15;
  const int wr = wave >> 1, wc = wave & 1;  // 2x2 wave grid, each 64x64

  // XCD-aware remap: xcd = bid&7 gets row-tiles {xcd, xcd+8, ...}.
  const int bid = blockIdx.y * 64 + blockIdx.x;
  const int xcd = bid & 7;
  const int idx = bid >> 3;                 // 0..127
  const int rowTile = (idx & 7) * 8 + xcd;  // 0..63
  const int colSplit = idx >> 3;            // 0..15
  const int row0 = rowTile * BM;
  const int col0 = colSplit * CPB;

  // Staging (per half h, j in {0,1}): 1KB load covers rows wave*32+j*16+rsub,
  // stored octet p = lane&3, source octet q = p ^ ((rsub>>1)&3).
  const int rsub = lane >> 2;
  const int qsrc = (lane & 3) ^ ((rsub >> 1) & 3);
  const u8* aBase = Aq + (size_t)(row0 + wave * 32 + rsub) * DDIM + qsrc * 16;
  const int ldsOff = (wave * 32) * 64;   // byte offset of this wave's rows

  // Fragment reads: row R = w*64 + i*16 + l16; k-octet quad stored at
  // quad ^ ((l16>>1)&3); one ds_read_b128 per fragment.
  const int sw = (l16 >> 1) & 3;
  const int fragOff = (wr * 64 + l16) * 64 + ((quad ^ sw) * 16);
  const int fragOffB = (wc * 64 + l16) * 64 + ((quad ^ sw) * 16);

  for (int t = 0; t < TPB; ++t) {
    const u8* bBase = Bq + (size_t)(col0 + t * BN + wave * 32 + rsub) * DDIM + qsrc * 16;

    i32x4 acc[4][4];
#pragma unroll
    for (int mi = 0; mi < 4; ++mi)
#pragma unroll
      for (int ni = 0; ni < 4; ++ni) acc[mi][ni] = (i32x4){0, 0, 0, 0};

    for (int kk = 0; kk < DDIM; kk += BKC) {
      __syncthreads();  // previous round's readers done
#pragma unroll
      for (int h = 0; h < 2; ++h) {
#pragma unroll
        for (int j = 0; j < 2; ++j) {
          gl2lds16(aBase + j * 16 * DDIM + kk + h * 64, &sA[h][ldsOff + j * 1024]);
          gl2lds16(bBase + j * 16 * DDIM + kk + h * 64, &sB[h][ldsOff + j * 1024]);
        }
      }
      __syncthreads();  // staging complete (barrier drains vmcnt)

#pragma unroll
      for (int h = 0; h < 2; ++h) {
        i32x4 af[4], bq[4];
#pragma unroll
        for (int i = 0; i < 4; ++i) {
          af[i] = *(const i32x4*)(&sA[h][fragOff + i * 16 * 64]);
          bq[i] = *(const i32x4*)(&sB[h][fragOffB + i * 16 * 64]);
        }
#pragma unroll
        for (int mi = 0; mi < 4; ++mi)
#pragma unroll
          for (int ni = 0; ni < 4; ++ni)
            acc[mi][ni] =
                __builtin_amdgcn_mfma_i32_16x16x64_i8(af[mi], bq[ni], acc[mi][ni], 0, 0, 0);
      }
    }

    // Per-tile LSE: dequant+1/T, shfl-merge over 16 l16 lanes, stash (m,l)
    // in LDS slot [t*2+wc] (merged once per block at the end).
#pragma unroll
    for (int mi = 0; mi < 4; ++mi) {
#pragma unroll
      for (int r = 0; r < 4; ++r) {
        float v0 = (float)acc[mi][0][r] * OUT_SCALE;
        float v1 = (float)acc[mi][1][r] * OUT_SCALE;
        float v2 = (float)acc[mi][2][r] * OUT_SCALE;
        float v3 = (float)acc[mi][3][r] * OUT_SCALE;
        float mx = fmaxf(fmaxf(v0, v1), fmaxf(v2, v3));
        mx = fmaxf(mx, __shfl_xor(mx, 1));
        mx = fmaxf(mx, __shfl_xor(mx, 2));
        mx = fmaxf(mx, __shfl_xor(mx, 4));
        mx = fmaxf(mx, __shfl_xor(mx, 8));
        float s = __expf(v0 - mx) + __expf(v1 - mx) + __expf(v2 - mx) + __expf(v3 - mx);
        s += __shfl_xor(s, 1);
        s += __shfl_xor(s, 2);
        s += __shfl_xor(s, 4);
        s += __shfl_xor(s, 8);
        if (l16 == 0) {
          int rowl = wr * 64 + mi * 16 + quad * 4 + r;
          sPm[t * 2 + wc][rowl] = mx;
          sPs[t * 2 + wc][rowl] = s;
        }
      }
    }
  }

  // Block-level merge of the 8 tile partials -> one (m,l) per row.
  __syncthreads();
  if (tid < BM) {
    float m = sPm[0][tid], l = sPs[0][tid];
#pragma unroll
    for (int s = 1; s < 2 * TPB; ++s) {
      float om = sPm[s][tid], ol = sPs[s][tid];
      float nm = fmaxf(m, om);
      l = l * __expf(m - nm) + ol * __expf(om - nm);
      m = nm;
    }
    partM[(size_t)colSplit * NB + row0 + tid] = m;
    partL[(size_t)colSplit * NB + row0 + tid] = l;
  }
}

// One row per thread, 32 blocks; block-sum -> atomicAdd.
__global__ void reduce_kernel(const float* __restrict__ partM,
                              const float* __restrict__ partL,
                              const float* __restrict__ diag, float* __restrict__ out) {
  __shared__ float red[4];
  int r = blockIdx.x * 256 + threadIdx.x;
  float M = -INFINITY;
#pragma unroll
  for (int s = 0; s < NPART; ++s) M = fmaxf(M, partM[(size_t)s * NB + r]);
  float L = 0.f;
#pragma unroll
  for (int s = 0; s < NPART; ++s)
    L += partL[(size_t)s * NB + r] * __expf(partM[(size_t)s * NB + r] - M);
  float v = M + __logf(L) - diag[r];
  for (int off = 32; off > 0; off >>= 1) v += __shfl_down(v, off);
  if ((threadIdx.x & 63) == 0) red[threadIdx.x >> 6] = v;
  __syncthreads();
  if (threadIdx.x == 0) {
    float s = (red[0] + red[1] + red[2] + red[3]) * (1.0f / (float)NB);
    atomicAdd(out, s);
  }
}

extern "C" void kernel_launch(void* const* d_in, const int* in_sizes, int n_in,
                              void* d_out, int out_size, void* d_ws, size_t ws_size,
                              hipStream_t stream) {
  const float* anchor = (const float*)d_in[0];
  const float* positive = (const float*)d_in[1];
  float* out = (float*)d_out;

  char* ws = (char*)d_ws;
  u8* Aq = (u8*)ws;                                      // 4 MB
  u8* Bq = (u8*)(ws + (size_t)4194304);                  // 4 MB
  float* diag = (float*)(ws + (size_t)8388608);          // 32 KB
  float* partM = (float*)(ws + (size_t)8388608 + 32768);             // 512 KB
  float* partL = (float*)(ws + (size_t)8388608 + 32768 + (size_t)NPART * NB * 4);

  cvt_diag_kernel<<<NB / 4, 256, 0, stream>>>(anchor, positive, Aq, Bq, diag, out);
  gemm_lse<<<dim3(64, SPLITS), 256, 0, stream>>>(Aq, Bq, partM, partL);
  reduce_kernel<<<NB / 256, 256, 0, stream>>>(partM, partL, diag, out);
}